// Round 8
// baseline (185.165 us; speedup 1.0000x reference)
//
#include <hip/hip_runtime.h>

#define TW 64        // tile width  (lap pixels)
#define TH 32        // tile height
#define DR 18        // down rows incl. 1-ring halo (TH/2 + 2)
#define DC 34        // down cols incl. halo (TW/2 + 2)
#define SDP 35       // s_down row stride (odd -> bank spread)
#define NTASK (DR * 17)   // 306 down-pair tasks per tile

typedef float vf4 __attribute__((ext_vector_type(4)));

__device__ __forceinline__ int refl(int t, int n) {
    if (t < 0) t = -t;
    if (t >= n) t = 2 * (n - 1) - t;
    return t;
}

__device__ __forceinline__ void nt_store4(float x, float y, float z, float w, float* p) {
    vf4 v = {x, y, z, w};
    __builtin_nontemporal_store(v, (vf4*)p);
}

// One fused pyramid level: down = gauss5(cur)[::2,::2]; lap = cur - up(down).
// Single-barrier structure: per thread, prefetch lap's cur pixels (2 float4),
// then compute a pair of down values straight from global (10 independent
// float4 loads, separable filter in registers) -> s_down (2.5KB LDS) ->
// barrier -> up-stencil + subtract from prefetched cur. Halo down values
// follow the chain convention (reflect inherited from reflected reads +
// kernel symmetry), exactly what the up-stencil needs (validated R3-R6).
__global__ __launch_bounds__(256, 8) void lap_level_kernel(
    const float* __restrict__ cur, float* __restrict__ lap,
    float* __restrict__ down, int H, int W)
{
    __shared__ float s_down[DR][SDP];

    const int x0 = blockIdx.x * TW, y0 = blockIdx.y * TH;
    const int img = blockIdx.z;
    const int Hh = H >> 1, Wh = W >> 1;
    const int tid = threadIdx.x;
    const int tx = tid & 15, ty = tid >> 4;

    const float* curb = cur + (size_t)img * H * W;

    // ---- P: prefetch this thread's lap cur pixels (always in-image) ----
    const int i0 = y0 + 2 * ty, j0 = x0 + 4 * tx;
    const float* cvp = curb + (size_t)i0 * W + j0;
    const float4 cve = *(const float4*)(cvp);
    const float4 cvo = *(const float4*)(cvp + (size_t)W);

    // ---- B: down pairs directly from global ----
    float* downb = down + (size_t)img * Hh * Wh;
    const bool border = (x0 == 0) | (y0 == 0) | (x0 + TW == W) | (y0 + TH == H);
    if (!border) {
        for (int k = tid; k < NTASK; k += 256) {
            unsigned a = (unsigned)k / 17u;
            unsigned b2 = (unsigned)k - a * 17u;
            const float* p = curb + (size_t)(y0 - 4 + 2 * (int)a) * W + (x0 - 4 + 4 * (int)b2);
            float4 A0 = *(const float4*)(p);
            float4 B0 = *(const float4*)(p + 4);
            float4 A1 = *(const float4*)(p + (size_t)W);
            float4 B1 = *(const float4*)(p + (size_t)W + 4);
            float4 A2 = *(const float4*)(p + (size_t)2 * W);
            float4 B2 = *(const float4*)(p + (size_t)2 * W + 4);
            float4 A3 = *(const float4*)(p + (size_t)3 * W);
            float4 B3 = *(const float4*)(p + (size_t)3 * W + 4);
            float4 A4 = *(const float4*)(p + (size_t)4 * W);
            float4 B4 = *(const float4*)(p + (size_t)4 * W + 4);
            // vertical 5-tap column sums (7 cols used)
            float s0 = A0.x + 4.f * A1.x + 6.f * A2.x + 4.f * A3.x + A4.x;
            float s1 = A0.y + 4.f * A1.y + 6.f * A2.y + 4.f * A3.y + A4.y;
            float s2 = A0.z + 4.f * A1.z + 6.f * A2.z + 4.f * A3.z + A4.z;
            float s3 = A0.w + 4.f * A1.w + 6.f * A2.w + 4.f * A3.w + A4.w;
            float s4 = B0.x + 4.f * B1.x + 6.f * B2.x + 4.f * B3.x + B4.x;
            float s5 = B0.y + 4.f * B1.y + 6.f * B2.y + 4.f * B3.y + B4.y;
            float s6 = B0.z + 4.f * B1.z + 6.f * B2.z + 4.f * B3.z + B4.z;
            float v0 = (s0 + 4.f * s1 + 6.f * s2 + 4.f * s3 + s4) * (1.f / 256.f);
            float v1 = (s2 + 4.f * s3 + 6.f * s4 + 4.f * s5 + s6) * (1.f / 256.f);
            s_down[a][2 * b2] = v0;
            s_down[a][2 * b2 + 1] = v1;
            if (a - 1u < 16u) {
                size_t rowoff = (size_t)((y0 >> 1) - 1 + (int)a) * Wh + ((x0 >> 1) - 1);
                if (b2 >= 1u) downb[rowoff + 2 * b2] = v0;
                if (b2 <= 15u) downb[rowoff + 2 * b2 + 1] = v1;
            }
        }
    } else {
        for (int k = tid; k < NTASK; k += 256) {
            unsigned a = (unsigned)k / 17u;
            unsigned b2 = (unsigned)k - a * 17u;
            const float wv[5] = {1.f, 4.f, 6.f, 4.f, 1.f};
            float s[7];
#pragma unroll
            for (int c = 0; c < 7; ++c) {
                int gx = refl(x0 - 4 + 4 * (int)b2 + c, W);
                float acc = 0.f;
#pragma unroll
                for (int u = 0; u < 5; ++u)
                    acc += wv[u] * curb[(size_t)refl(y0 - 4 + 2 * (int)a + u, H) * W + gx];
                s[c] = acc;
            }
            float v0 = (s[0] + 4.f * s[1] + 6.f * s[2] + 4.f * s[3] + s[4]) * (1.f / 256.f);
            float v1 = (s[2] + 4.f * s[3] + 6.f * s[4] + 4.f * s[5] + s[6]) * (1.f / 256.f);
            s_down[a][2 * b2] = v0;
            s_down[a][2 * b2 + 1] = v1;
            if (a - 1u < 16u) {
                size_t rowoff = (size_t)((y0 >> 1) - 1 + (int)a) * Wh + ((x0 >> 1) - 1);
                if (b2 >= 1u) downb[rowoff + 2 * b2] = v0;
                if (b2 <= 15u) downb[rowoff + 2 * b2 + 1] = v1;
            }
        }
    }
    __syncthreads();

    // ---- C: lap = cur - up(down); thread = 4 wide x 2 tall; parity static ----
    float d0[4], d1[4], d2[4];
#pragma unroll
    for (int c = 0; c < 4; ++c) {
        d0[c] = s_down[ty + 0][2 * tx + c];
        d1[c] = s_down[ty + 1][2 * tx + c];
        d2[c] = s_down[ty + 2][2 * tx + c];
    }
    float ce[4], co[4];
#pragma unroll
    for (int c = 0; c < 4; ++c) {
        ce[c] = d0[c] + 6.f * d1[c] + d2[c];
        co[c] = 4.f * (d1[c] + d2[c]);
    }
    float* lapb = lap + (size_t)img * H * W;
    nt_store4(cve.x - (ce[0] + 6.f * ce[1] + ce[2]) * (1.f / 64.f),
              cve.y - 4.f * (ce[1] + ce[2]) * (1.f / 64.f),
              cve.z - (ce[1] + 6.f * ce[2] + ce[3]) * (1.f / 64.f),
              cve.w - 4.f * (ce[2] + ce[3]) * (1.f / 64.f),
              lapb + (size_t)i0 * W + j0);
    nt_store4(cvo.x - (co[0] + 6.f * co[1] + co[2]) * (1.f / 64.f),
              cvo.y - 4.f * (co[1] + co[2]) * (1.f / 64.f),
              cvo.z - (co[1] + 6.f * co[2] + co[3]) * (1.f / 64.f),
              cvo.w - 4.f * (co[2] + co[3]) * (1.f / 64.f),
              lapb + (size_t)(i0 + 1) * W + j0);
}

extern "C" void kernel_launch(void* const* d_in, const int* in_sizes, int n_in,
                              void* d_out, int out_size, void* d_ws, size_t ws_size,
                              hipStream_t stream) {
    const float* img = (const float*)d_in[0];
    float* out = (float*)d_out;

    const long long BC = 8LL * 3;
    const long long n0 = BC * 1024 * 1024;
    const long long n1 = BC * 512 * 512;
    const long long n2 = BC * 256 * 256;

    float* out0 = out;            // lap0
    float* out1 = out0 + n0;      // lap1
    float* out2 = out1 + n1;      // lap2
    float* out3 = out2 + n2;      // down2

    float* ws0 = (float*)d_ws;    // down0
    float* ws1 = ws0 + n1;        // down1

    lap_level_kernel<<<dim3(1024 / TW, 1024 / TH, (int)BC), 256, 0, stream>>>(
        img, out0, ws0, 1024, 1024);
    lap_level_kernel<<<dim3(512 / TW, 512 / TH, (int)BC), 256, 0, stream>>>(
        ws0, out1, ws1, 512, 512);
    lap_level_kernel<<<dim3(256 / TW, 256 / TH, (int)BC), 256, 0, stream>>>(
        ws1, out2, out3, 256, 256);
}